// Round 6
// baseline (311.492 us; speedup 1.0000x reference)
//
#include <hip/hip_runtime.h>

#define TOK 8192   // B*S
#define DIM 512    // D
#define NE  32     // experts
#define KTOT (NE * DIM)

#define BM 128
#define BN 128
#define BK 64

typedef float f32x4 __attribute__((ext_vector_type(4)));
typedef short s16x8 __attribute__((ext_vector_type(8)));

typedef const void __attribute__((address_space(1)))* gp1_t;
typedef void __attribute__((address_space(3)))* lp3_t;

__device__ __forceinline__ void gl_lds16(const void* g, void* l) {
    __builtin_amdgcn_global_load_lds((gp1_t)g, (lp3_t)l, 16, 0, 0);
}

__device__ __forceinline__ ushort f2bf(float f) {
    unsigned u = __builtin_bit_cast(unsigned, f);
    unsigned r = (u + 0x7fffu + ((u >> 16) & 1u)) >> 16;
    return (ushort)r;
}

// ---- expert_w [E][D][F] fp32 -> Wt [F][E*D] bf16, 64x64 tiles ----
__global__ __launch_bounds__(256) void k_cvt_wt(const float* __restrict__ w,
                                                ushort* __restrict__ wt) {
    __shared__ float tile[64][65];
    const int e = blockIdx.z;
    const int f0 = blockIdx.x * 64;
    const int d0 = blockIdx.y * 64;
    const int tx = threadIdx.x & 63, ty = threadIdx.x >> 6;  // ty 0..3
    const float* we = w + (size_t)e * DIM * DIM;
#pragma unroll
    for (int i = ty; i < 64; i += 4)
        tile[i][tx] = we[(size_t)(d0 + i) * DIM + f0 + tx];
    __syncthreads();
#pragma unroll
    for (int i = ty; i < 64; i += 4)
        wt[(size_t)(f0 + i) * KTOT + e * DIM + d0 + tx] = f2bf(tile[tx][i]);
}

// ---- gates (8 tokens/block, shfl softmax) + x fp32->bf16 conversion ----
__global__ __launch_bounds__(256) void k_gates(const float* __restrict__ x,
                                               const float* __restrict__ gw,
                                               const float* __restrict__ gb,
                                               float* __restrict__ G,
                                               ushort* __restrict__ xb) {
    __shared__ float xs[8 * DIM];
    const int t0 = blockIdx.x * 8;
    const int tid = threadIdx.x;
    const float* xBase = x + (size_t)t0 * DIM;
#pragma unroll
    for (int k = 0; k < 4; ++k) {
        int i4 = (k * 256 + tid) * 4;
        float4 v = *(const float4*)(xBase + i4);
        xs[i4 + 0] = v.x; xs[i4 + 1] = v.y; xs[i4 + 2] = v.z; xs[i4 + 3] = v.w;
        ushort4 o;
        o.x = f2bf(v.x); o.y = f2bf(v.y); o.z = f2bf(v.z); o.w = f2bf(v.w);
        *(ushort4*)(xb + (size_t)t0 * DIM + i4) = o;
    }
    __syncthreads();
    const int tok = tid >> 5;   // 0..7
    const int e = tid & 31;
    float l = gb[e];
    const float* xr = xs + tok * DIM;
#pragma unroll 8
    for (int d = 0; d < DIM; ++d)
        l += xr[d] * gw[d * NE + e];
    // softmax across the 32-lane group (masks <=16 stay inside the group)
    float mx = l;
#pragma unroll
    for (int m = 16; m >= 1; m >>= 1) mx = fmaxf(mx, __shfl_xor(mx, m));
    float ex = expf(l - mx);
    float s = ex;
#pragma unroll
    for (int m = 16; m >= 1; m >>= 1) s += __shfl_xor(s, m);
    G[(size_t)(t0 + tok) * NE + e] = ex / s;
}

// ============ main GEMM v2: 4 waves of 64x64, z=4 expert split =============
// Per (expert,kt): stage 16KB A + 16KB B (swizzled), read 8 a-frags + 8
// b-frags (0.5 reads/MFMA), chain 2 MFMAs per (i,j) into a 4-reg transient,
// fold immediately with per-expert gate regs (no persistent pacc).
__global__ __launch_bounds__(256, 3) void k_moe_gemm4(const ushort* __restrict__ xb,
                                                      const ushort* __restrict__ wt,
                                                      const float* __restrict__ G,
                                                      float* __restrict__ out,
                                                      float* __restrict__ P1,
                                                      float* __restrict__ P2,
                                                      float* __restrict__ P3) {
    __shared__ __align__(16) ushort As[BM * BK];   // 16 KB
    __shared__ __align__(16) ushort Bs[BN * BK];   // 16 KB
    __shared__ float Gs[8][BM];                    // 4 KB, [expert][row]

    const int tid = threadIdx.x;
    const int m0 = blockIdx.y * BM;
    const int n0 = blockIdx.x * BN;
    const int z = blockIdx.z;
    const int e0 = z * 8;
    float* __restrict__ dst = (z == 0) ? out : (z == 1) ? P1 : (z == 2) ? P2 : P3;

    for (int i = tid; i < 8 * BM; i += 256) {
        int e = i & 7, r = i >> 3;
        Gs[e][r] = G[(size_t)(m0 + r) * NE + e0 + e];
    }

    const int lane = tid & 63;
    const int wave = tid >> 6;            // 0..3
    const int wm = (wave & 1) * 64;
    const int wn = (wave >> 1) * 64;
    const int l15 = lane & 15;
    const int q = lane >> 4;              // 0..3
    const int keyR = l15 & 7;

    // un-swizzle chunk byte offsets for the two K-halves
    const int swz0 = ((0 * 4 + q) ^ keyR) * 16;
    const int swz1 = ((1 * 4 + q) ^ keyR) * 16;
    // reader byte addresses (loop-invariant)
    int ra[4][2], rb[4][2];
#pragma unroll
    for (int i = 0; i < 4; ++i) {
        ra[i][0] = (wm + i * 16 + l15) * 128 + swz0;
        ra[i][1] = (wm + i * 16 + l15) * 128 + swz1;
        rb[i][0] = (wn + i * 16 + l15) * 128 + swz0;
        rb[i][1] = (wn + i * 16 + l15) * 128 + swz1;
    }

    const f32x4 zv = {0.f, 0.f, 0.f, 0.f};
    f32x4 acc[4][4];
#pragma unroll
    for (int i = 0; i < 4; ++i)
#pragma unroll
        for (int j = 0; j < 4; ++j) acc[i][j] = zv;

    // staging: 256 thr x 16B = 4KB/round, 4 rounds per 16KB tile (R3-proven)
    const int srow = tid >> 3;                       // 0..31
    const int chunk = tid & 7;
    const int scol = ((chunk ^ (srow & 7)) * 8);     // swizzled global column
    const ushort* aBase = xb + (size_t)(m0 + srow) * DIM + scol;
    const ushort* bBase = wt + (size_t)(n0 + srow) * KTOT + scol;
    char* aLds = (char*)As + tid * 16;
    char* bLds = (char*)Bs + tid * 16;

    __syncthreads();   // Gs visible

#pragma unroll 1
    for (int ee = 0; ee < 8; ++ee) {
        const int e = e0 + ee;
        f32x4 gt[4];
#pragma unroll
        for (int i = 0; i < 4; ++i)
            gt[i] = *(const f32x4*)&Gs[ee][wm + i * 16 + q * 4];

#pragma unroll 1
        for (int kt = 0; kt < 8; ++kt) {
            const int kd = kt * BK;
            const ushort* aS = aBase + kd;
            const ushort* bS = bBase + (size_t)e * DIM + kd;
#pragma unroll
            for (int r = 0; r < 4; ++r) {
                gl_lds16(aS + (size_t)r * 32 * DIM, aLds + r * 4096);
                gl_lds16(bS + (size_t)r * 32 * KTOT, bLds + r * 4096);
            }
            __syncthreads();

            s16x8 a[4][2];
#pragma unroll
            for (int i = 0; i < 4; ++i) {
                a[i][0] = *(const s16x8*)((const char*)As + ra[i][0]);
                a[i][1] = *(const s16x8*)((const char*)As + ra[i][1]);
            }
#pragma unroll
            for (int j = 0; j < 4; ++j) {
                s16x8 b0 = *(const s16x8*)((const char*)Bs + rb[j][0]);
                s16x8 b1 = *(const s16x8*)((const char*)Bs + rb[j][1]);
#pragma unroll
                for (int i = 0; i < 4; ++i) {
                    f32x4 p = __builtin_amdgcn_mfma_f32_16x16x32_bf16(
                        a[i][0], b0, zv, 0, 0, 0);
                    p = __builtin_amdgcn_mfma_f32_16x16x32_bf16(
                        a[i][1], b1, p, 0, 0, 0);
                    acc[i][j][0] += gt[i][0] * p[0];
                    acc[i][j][1] += gt[i][1] * p[1];
                    acc[i][j][2] += gt[i][2] * p[2];
                    acc[i][j][3] += gt[i][3] * p[3];
                }
            }
            __syncthreads();
        }
    }

    // epilogue: plain stores (each element of dst owned by exactly one lane)
#pragma unroll
    for (int i = 0; i < 4; ++i) {
        const int tl = m0 + wm + i * 16 + q * 4;
#pragma unroll
        for (int j = 0; j < 4; ++j) {
            const int f = n0 + wn + j * 16 + l15;
            float* p = dst + (size_t)tl * DIM + f;
            p[0 * DIM] = acc[i][j][0];
            p[1 * DIM] = acc[i][j][1];
            p[2 * DIM] = acc[i][j][2];
            p[3 * DIM] = acc[i][j][3];
        }
    }
}

// ================== fallback GEMM (R5, proven 146.5 us) ====================
__global__ __launch_bounds__(512, 2) void k_moe_gemm(const ushort* __restrict__ xb,
                                                     const ushort* __restrict__ wt,
                                                     const float* __restrict__ G,
                                                     float* __restrict__ out0,
                                                     float* __restrict__ out1) {
    __shared__ __align__(16) ushort As[BM * BK];
    __shared__ __align__(16) ushort Bs[BN * BK];
    __shared__ float Gs[BM][17];

    const int tid = threadIdx.x;
    const int m0 = blockIdx.y * BM;
    const int n0 = blockIdx.x * BN;
    const int e0 = blockIdx.z * 16;
    float* __restrict__ dst = blockIdx.z ? out1 : out0;

    for (int i = tid; i < BM * 16; i += 512) {
        int r = i >> 4, c = i & 15;
        Gs[r][c] = G[(size_t)(m0 + r) * NE + e0 + c];
    }

    const int lane = tid & 63;
    const int wave = tid >> 6;
    const int wm = (wave & 3) * 32;
    const int wn = (wave >> 2) * 64;
    const int l15 = lane & 15;
    const int q = lane >> 4;
    const int keyR = l15 & 7;

    const f32x4 zv = {0.f, 0.f, 0.f, 0.f};
    f32x4 acc[2][4];
#pragma unroll
    for (int i = 0; i < 2; ++i)
#pragma unroll
        for (int j = 0; j < 4; ++j) acc[i][j] = zv;

    const int srow = tid >> 3;
    const int chunk = tid & 7;
    const int scol = ((chunk ^ (srow & 7)) * 8);
    const ushort* aBase = xb + (size_t)(m0 + srow) * DIM + scol;
    const ushort* bBase = wt + (size_t)(n0 + srow) * KTOT + scol;
    char* aLds = (char*)As + tid * 16;
    char* bLds = (char*)Bs + tid * 16;

#pragma unroll 1
    for (int ee = 0; ee < 16; ++ee) {
        const int e = e0 + ee;
        f32x4 pacc[2][4];
#pragma unroll
        for (int i = 0; i < 2; ++i)
#pragma unroll
            for (int j = 0; j < 4; ++j) pacc[i][j] = zv;

#pragma unroll 1
        for (int kt = 0; kt < 8; ++kt) {
            const int kd = kt * BK;
            const ushort* aS = aBase + kd;
            const ushort* bS = bBase + (size_t)e * DIM + kd;
            gl_lds16(aS, aLds);
            gl_lds16(aS + (size_t)64 * DIM, aLds + 8192);
            gl_lds16(bS, bLds);
            gl_lds16(bS + (size_t)64 * KTOT, bLds + 8192);
            __syncthreads();
#pragma unroll
            for (int ks = 0; ks < 2; ++ks) {
                const int swz = ((ks * 4 + q) ^ keyR) * 16;
                s16x8 a[2], b[4];
#pragma unroll
                for (int i = 0; i < 2; ++i)
                    a[i] = *(const s16x8*)((const char*)As +
                           (wm + i * 16 + l15) * (BK * 2) + swz);
#pragma unroll
                for (int j = 0; j < 4; ++j)
                    b[j] = *(const s16x8*)((const char*)Bs +
                           (wn + j * 16 + l15) * (BK * 2) + swz);
#pragma unroll
                for (int i = 0; i < 2; ++i)
#pragma unroll
                    for (int j = 0; j < 4; ++j)
                        pacc[i][j] = __builtin_amdgcn_mfma_f32_16x16x32_bf16(
                            a[i], b[j], pacc[i][j], 0, 0, 0);
            }
            __syncthreads();
        }

#pragma unroll
        for (int i = 0; i < 2; ++i) {
            const int tl = wm + i * 16 + q * 4;
            const float g0 = Gs[tl + 0][ee];
            const float g1 = Gs[tl + 1][ee];
            const float g2 = Gs[tl + 2][ee];
            const float g3 = Gs[tl + 3][ee];
#pragma unroll
            for (int j = 0; j < 4; ++j) {
                acc[i][j][0] += g0 * pacc[i][j][0];
                acc[i][j][1] += g1 * pacc[i][j][1];
                acc[i][j][2] += g2 * pacc[i][j][2];
                acc[i][j][3] += g3 * pacc[i][j][3];
            }
        }
    }

#pragma unroll
    for (int i = 0; i < 2; ++i) {
        const int tl = m0 + wm + i * 16 + q * 4;
#pragma unroll
        for (int j = 0; j < 4; ++j) {
            const int f = n0 + wn + j * 16 + l15;
            float* p = dst + (size_t)tl * DIM + f;
            p[0 * DIM] = acc[i][j][0];
            p[1 * DIM] = acc[i][j][1];
            p[2 * DIM] = acc[i][j][2];
            p[3 * DIM] = acc[i][j][3];
        }
    }
}

// ---- deterministic partial sum: out += P1 (+P2 +P3), nP in {1,3} ----
__global__ __launch_bounds__(256) void k_reduce(float* __restrict__ out,
                                                const float* __restrict__ P1,
                                                const float* __restrict__ P2,
                                                const float* __restrict__ P3,
                                                int nP) {
    int i = (blockIdx.x * 256 + threadIdx.x) * 4;
    float4 a = *(const float4*)(out + i);
    float4 b = *(const float4*)(P1 + i);
    a.x += b.x; a.y += b.y; a.z += b.z; a.w += b.w;
    if (nP == 3) {
        float4 c = *(const float4*)(P2 + i);
        float4 d = *(const float4*)(P3 + i);
        a.x += c.x + d.x; a.y += c.y + d.y; a.z += c.z + d.z; a.w += c.w + d.w;
    }
    *(float4*)(out + i) = a;
}

extern "C" void kernel_launch(void* const* d_in, const int* in_sizes, int n_in,
                              void* d_out, int out_size, void* d_ws, size_t ws_size,
                              hipStream_t stream) {
    const float* x  = (const float*)d_in[0];   // [8192][512]
    const float* gw = (const float*)d_in[1];   // [512][32]
    const float* gb = (const float*)d_in[2];   // [32]
    const float* w  = (const float*)d_in[3];   // [32][512][512]
    float* out = (float*)d_out;                // [8192][512] fp32

    char* ws = (char*)d_ws;
    ushort* xb = (ushort*)ws;                            //  0..8 MiB
    ushort* wt = (ushort*)(ws + (8u << 20));             //  8..24 MiB
    float*  G  = (float*)(ws + (24u << 20));             // 24..25 MiB
    float*  P1 = (float*)(ws + (25u << 20));             // 25..41 MiB
    float*  P2 = (float*)(ws + (41u << 20));             // 41..57 MiB
    float*  P3 = (float*)(ws + (57u << 20));             // 57..73 MiB

    k_cvt_wt<<<dim3(8, 8, NE), dim3(256), 0, stream>>>(w, wt);
    k_gates<<<dim3(TOK / 8), dim3(256), 0, stream>>>(x, gw, gb, G, xb);

    if (ws_size >= ((size_t)73u << 20)) {
        k_moe_gemm4<<<dim3(DIM / BN, TOK / BM, 4), dim3(256), 0, stream>>>(
            xb, wt, G, out, P1, P2, P3);
        k_reduce<<<dim3(TOK * DIM / 1024), dim3(256), 0, stream>>>(out, P1, P2, P3, 3);
    } else {
        k_moe_gemm<<<dim3(DIM / BN, TOK / BM, 2), dim3(512), 0, stream>>>(
            xb, wt, G, out, P1);
        k_reduce<<<dim3(TOK * DIM / 1024), dim3(256), 0, stream>>>(out, P1, P1, P1, 1);
    }
}

// Round 7
// 255.742 us; speedup vs baseline: 1.2180x; 1.2180x over previous
//
#include <hip/hip_runtime.h>

#define TOK 8192   // B*S
#define DIM 512    // D
#define NE  32     // experts
#define KTOT (NE * DIM)

#define BM 128
#define BN 128
#define BK 64

typedef float f32x4 __attribute__((ext_vector_type(4)));
typedef short s16x8 __attribute__((ext_vector_type(8)));

typedef const void __attribute__((address_space(1)))* gp1_t;
typedef void __attribute__((address_space(3)))* lp3_t;

__device__ __forceinline__ void gl_lds16(const void* g, void* l) {
    __builtin_amdgcn_global_load_lds((gp1_t)g, (lp3_t)l, 16, 0, 0);
}

__device__ __forceinline__ ushort f2bf(float f) {
    unsigned u = __builtin_bit_cast(unsigned, f);
    unsigned r = (u + 0x7fffu + ((u >> 16) & 1u)) >> 16;
    return (ushort)r;
}

// ---- fused prep: blocks [0,2048) transpose+convert W; [2048,3072) gates+cvt x
__global__ __launch_bounds__(256) void k_prep(const float* __restrict__ w,
                                              ushort* __restrict__ wt,
                                              const float* __restrict__ x,
                                              const float* __restrict__ gw,
                                              const float* __restrict__ gb,
                                              float* __restrict__ G,
                                              ushort* __restrict__ xb) {
    __shared__ __align__(16) char smem[64 * 65 * 4];
    const int bx = blockIdx.x;
    const int tid = threadIdx.x;
    if (bx < 2048) {
        // ---- Wt[f][e*512+d] = bf16(w[e][d][f]), 64x64 tile ----
        float (*tile)[65] = (float(*)[65])smem;
        const int e = bx >> 6;
        const int f0 = ((bx >> 3) & 7) * 64;
        const int d0 = (bx & 7) * 64;
        const int tx = tid & 63, ty = tid >> 6;  // ty 0..3
        const float* we = w + (size_t)e * DIM * DIM;
#pragma unroll
        for (int i = ty; i < 64; i += 4)
            tile[i][tx] = we[(size_t)(d0 + i) * DIM + f0 + tx];
        __syncthreads();
#pragma unroll
        for (int i = ty; i < 64; i += 4)
            wt[(size_t)(f0 + i) * KTOT + e * DIM + d0 + tx] = f2bf(tile[tx][i]);
    } else {
        // ---- gates (8 tokens/block, shfl softmax) + x -> bf16 ----
        float* xs = (float*)smem;
        const int t0 = (bx - 2048) * 8;
        const float* xBase = x + (size_t)t0 * DIM;
#pragma unroll
        for (int k = 0; k < 4; ++k) {
            int i4 = (k * 256 + tid) * 4;
            float4 v = *(const float4*)(xBase + i4);
            xs[i4 + 0] = v.x; xs[i4 + 1] = v.y; xs[i4 + 2] = v.z; xs[i4 + 3] = v.w;
            ushort4 o;
            o.x = f2bf(v.x); o.y = f2bf(v.y); o.z = f2bf(v.z); o.w = f2bf(v.w);
            *(ushort4*)(xb + (size_t)t0 * DIM + i4) = o;
        }
        __syncthreads();
        const int tok = tid >> 5;   // 0..7
        const int e = tid & 31;
        float l = gb[e];
        const float* xr = xs + tok * DIM;
#pragma unroll 8
        for (int d = 0; d < DIM; ++d)
            l += xr[d] * gw[d * NE + e];
        float mx = l;
#pragma unroll
        for (int m = 16; m >= 1; m >>= 1) mx = fmaxf(mx, __shfl_xor(mx, m));
        float ex = expf(l - mx);
        float s = ex;
#pragma unroll
        for (int m = 16; m >= 1; m >>= 1) s += __shfl_xor(s, m);
        G[(size_t)(t0 + tok) * NE + e] = ex / s;
    }
}

// ------------- main GEMM: kt-outer / e-inner, double-buffered LDS ----------
// R5 occupancy shape (512 thr, 8 waves of 32x64, z=2 expert split, 2 blk/CU).
// A staged once per kt (was: once per (e,kt)); B(e+1) DMA issued one-ahead so
// the barrier's vmcnt drain finds it complete. Fold per (kt,e) via transient
// pacc. LDS XOR-swizzle (R3-proven): LDS[row][c] = Glob[row][c ^ (row&7)].
__global__ __launch_bounds__(512, 2) void k_moe_gemm(const ushort* __restrict__ xb,
                                                     const ushort* __restrict__ wt,
                                                     const float* __restrict__ G,
                                                     float* __restrict__ out0,
                                                     float* __restrict__ out1) {
    __shared__ __align__(16) ushort As[2][BM * BK];   // 2 x 16 KB
    __shared__ __align__(16) ushort Bs[2][BN * BK];   // 2 x 16 KB
    __shared__ float Gs[16][BM];                      // 8 KB

    const int tid = threadIdx.x;
    const int m0 = blockIdx.y * BM;
    const int n0 = blockIdx.x * BN;
    const int e0 = blockIdx.z * 16;
    float* __restrict__ dst = blockIdx.z ? out1 : out0;

    for (int i = tid; i < 16 * BM; i += 512) {
        int e = i >> 7, r = i & 127;
        Gs[e][r] = G[(size_t)(m0 + r) * NE + e0 + e];
    }

    const int lane = tid & 63;
    const int wave = tid >> 6;            // 0..7
    const int wm = (wave & 3) * 32;       // 4 m-positions
    const int wn = (wave >> 2) * 64;      // 2 n-positions
    const int l15 = lane & 15;
    const int q = lane >> 4;              // 0..3
    const int keyR = l15 & 7;

    // reader byte offsets: row*128 + ((ks*4+q)^keyR)*16
    const int swz0 = ((q) ^ keyR) * 16;
    const int swz1 = ((4 + q) ^ keyR) * 16;
    const int rowA0 = (wm + l15) * 128;
    const int rowA1 = (wm + 16 + l15) * 128;
    const int rowB0 = (wn + l15) * 128;
    const int rowB1 = (wn + 16 + l15) * 128;
    const int rowB2 = (wn + 32 + l15) * 128;
    const int rowB3 = (wn + 48 + l15) * 128;

    // staging map: 512 thr x 16B = 8KB/round, 2 rounds per 16KB tile
    const int srow = tid >> 3;                       // 0..63 (row&7 == srow&7)
    const int chunk = tid & 7;
    const int scol = ((chunk ^ (srow & 7)) * 8);     // swizzled global column
    const ushort* aBase = xb + (size_t)(m0 + srow) * DIM + scol;
    const ushort* bBase = wt + (size_t)(n0 + srow) * KTOT + (size_t)e0 * DIM + scol;
    const int ldsOff = tid * 16;

    const f32x4 zv = {0.f, 0.f, 0.f, 0.f};
    f32x4 acc[2][4];
#pragma unroll
    for (int i = 0; i < 2; ++i)
#pragma unroll
        for (int j = 0; j < 4; ++j) acc[i][j] = zv;

    // prologue: stage A(kt=0) -> As[0], B(e=0,kt=0) -> Bs[0]
    gl_lds16(aBase, (char*)As[0] + ldsOff);
    gl_lds16(aBase + (size_t)64 * DIM, (char*)As[0] + 8192 + ldsOff);
    gl_lds16(bBase, (char*)Bs[0] + ldsOff);
    gl_lds16(bBase + (size_t)64 * KTOT, (char*)Bs[0] + 8192 + ldsOff);
    __syncthreads();

#pragma unroll 1
    for (int kt = 0; kt < 8; ++kt) {
        const char* Ab = (const char*)As[kt & 1];
#pragma unroll 1
        for (int ee = 0; ee < 16; ++ee) {
            // issue next-tile DMA (one ahead); barrier at end publishes it
            const int gn = kt * 16 + ee + 1;
            if (gn < 128) {
                const ushort* bN = bBase + (size_t)(gn & 15) * DIM + (gn >> 4) * BK;
                char* bL = (char*)Bs[gn & 1] + ldsOff;
                gl_lds16(bN, bL);
                gl_lds16(bN + (size_t)64 * KTOT, bL + 8192);
                if (ee == 15) {
                    const ushort* aN = aBase + (kt + 1) * BK;
                    char* aL = (char*)As[(kt + 1) & 1] + ldsOff;
                    gl_lds16(aN, aL);
                    gl_lds16(aN + (size_t)64 * DIM, aL + 8192);
                }
            }

            const char* Bb = (const char*)Bs[ee & 1];
            f32x4 pacc[2][4];
#pragma unroll
            for (int ks = 0; ks < 2; ++ks) {
                const int swz = ks ? swz1 : swz0;
                s16x8 a0 = *(const s16x8*)(Ab + rowA0 + swz);
                s16x8 a1 = *(const s16x8*)(Ab + rowA1 + swz);
                s16x8 b0 = *(const s16x8*)(Bb + rowB0 + swz);
                s16x8 b1 = *(const s16x8*)(Bb + rowB1 + swz);
                s16x8 b2 = *(const s16x8*)(Bb + rowB2 + swz);
                s16x8 b3 = *(const s16x8*)(Bb + rowB3 + swz);
                if (ks == 0) {
                    pacc[0][0] = __builtin_amdgcn_mfma_f32_16x16x32_bf16(a0, b0, zv, 0, 0, 0);
                    pacc[0][1] = __builtin_amdgcn_mfma_f32_16x16x32_bf16(a0, b1, zv, 0, 0, 0);
                    pacc[0][2] = __builtin_amdgcn_mfma_f32_16x16x32_bf16(a0, b2, zv, 0, 0, 0);
                    pacc[0][3] = __builtin_amdgcn_mfma_f32_16x16x32_bf16(a0, b3, zv, 0, 0, 0);
                    pacc[1][0] = __builtin_amdgcn_mfma_f32_16x16x32_bf16(a1, b0, zv, 0, 0, 0);
                    pacc[1][1] = __builtin_amdgcn_mfma_f32_16x16x32_bf16(a1, b1, zv, 0, 0, 0);
                    pacc[1][2] = __builtin_amdgcn_mfma_f32_16x16x32_bf16(a1, b2, zv, 0, 0, 0);
                    pacc[1][3] = __builtin_amdgcn_mfma_f32_16x16x32_bf16(a1, b3, zv, 0, 0, 0);
                } else {
                    pacc[0][0] = __builtin_amdgcn_mfma_f32_16x16x32_bf16(a0, b0, pacc[0][0], 0, 0, 0);
                    pacc[0][1] = __builtin_amdgcn_mfma_f32_16x16x32_bf16(a0, b1, pacc[0][1], 0, 0, 0);
                    pacc[0][2] = __builtin_amdgcn_mfma_f32_16x16x32_bf16(a0, b2, pacc[0][2], 0, 0, 0);
                    pacc[0][3] = __builtin_amdgcn_mfma_f32_16x16x32_bf16(a0, b3, pacc[0][3], 0, 0, 0);
                    pacc[1][0] = __builtin_amdgcn_mfma_f32_16x16x32_bf16(a1, b0, pacc[1][0], 0, 0, 0);
                    pacc[1][1] = __builtin_amdgcn_mfma_f32_16x16x32_bf16(a1, b1, pacc[1][1], 0, 0, 0);
                    pacc[1][2] = __builtin_amdgcn_mfma_f32_16x16x32_bf16(a1, b2, pacc[1][2], 0, 0, 0);
                    pacc[1][3] = __builtin_amdgcn_mfma_f32_16x16x32_bf16(a1, b3, pacc[1][3], 0, 0, 0);
                }
            }

            // fold with per-token gates (broadcast b128 reads from Gs)
#pragma unroll
            for (int i = 0; i < 2; ++i) {
                const f32x4 gt = *(const f32x4*)&Gs[ee][wm + i * 16 + q * 4];
#pragma unroll
                for (int j = 0; j < 4; ++j) {
                    acc[i][j][0] += gt[0] * pacc[i][j][0];
                    acc[i][j][1] += gt[1] * pacc[i][j][1];
                    acc[i][j][2] += gt[2] * pacc[i][j][2];
                    acc[i][j][3] += gt[3] * pacc[i][j][3];
                }
            }
            __syncthreads();   // publishes next buffers; DMA already complete
        }
    }

    // epilogue: plain stores (each element of dst owned by exactly one lane)
#pragma unroll
    for (int i = 0; i < 2; ++i) {
        const int tl = m0 + wm + i * 16 + q * 4;
#pragma unroll
        for (int j = 0; j < 4; ++j) {
            const int f = n0 + wn + j * 16 + l15;
            float* p = dst + (size_t)tl * DIM + f;
            p[0 * DIM] = acc[i][j][0];
            p[1 * DIM] = acc[i][j][1];
            p[2 * DIM] = acc[i][j][2];
            p[3 * DIM] = acc[i][j][3];
        }
    }
}

// ---- deterministic two-phase sum: out += P (both fully written upstream) ----
__global__ __launch_bounds__(256) void k_reduce(float* __restrict__ out,
                                                const float* __restrict__ P) {
    int i = (blockIdx.x * 256 + threadIdx.x) * 4;
    float4 a = *(const float4*)(out + i);
    float4 b = *(const float4*)(P + i);
    a.x += b.x; a.y += b.y; a.z += b.z; a.w += b.w;
    *(float4*)(out + i) = a;
}

extern "C" void kernel_launch(void* const* d_in, const int* in_sizes, int n_in,
                              void* d_out, int out_size, void* d_ws, size_t ws_size,
                              hipStream_t stream) {
    const float* x  = (const float*)d_in[0];   // [8192][512]
    const float* gw = (const float*)d_in[1];   // [512][32]
    const float* gb = (const float*)d_in[2];   // [32]
    const float* w  = (const float*)d_in[3];   // [32][512][512]
    float* out = (float*)d_out;                // [8192][512] fp32

    char* ws = (char*)d_ws;
    ushort* xb = (ushort*)ws;                            //  0..8 MiB
    ushort* wt = (ushort*)(ws + (8u << 20));             //  8..24 MiB
    float*  G  = (float*)(ws + (24u << 20));             // 24..25 MiB
    float*  P  = (float*)(ws + (25u << 20));             // 25..41 MiB

    k_prep<<<dim3(2048 + TOK / 8), dim3(256), 0, stream>>>(w, wt, x, gw, gb, G, xb);
    k_moe_gemm<<<dim3(DIM / BN, TOK / BM, 2), dim3(512), 0, stream>>>(xb, wt, G, out, P);
    k_reduce<<<dim3(TOK * DIM / 1024), dim3(256), 0, stream>>>(out, P);
}